// Round 12
// baseline (113.641 us; speedup 1.0000x reference)
//
#include <hip/hip_runtime.h>
#include <hip/hip_bf16.h>

typedef __bf16 bf16x8 __attribute__((ext_vector_type(8)));
typedef float  f32x4  __attribute__((ext_vector_type(4)));
typedef float  f32x16 __attribute__((ext_vector_type(16)));

#define BN_EPS 1e-5f
#define NROWS 131072
#define TPB 256               // 4 waves: rg=wave>>1 (64-row group), cg=wave&1 (128-col group)
#define BM 128                // rows per block
#define NBLOCKS (NROWS / BM)  // 1024

#define WAITVM(N) asm volatile("s_waitcnt vmcnt(" #N ")" ::: "memory")

__device__ __forceinline__ void gll16(const void* g, void* l) {
    __builtin_amdgcn_global_load_lds(
        (const __attribute__((address_space(1))) void*)g,
        (__attribute__((address_space(3))) void*)l, 16, 0, 0);
}

// ws layout (bytes):
//   [0, 262144)        W0a packed bf16 (BN scale a folded in) for 32x32x16 B-frags:
//                      flat = ((s*8 + t)*64 + lane)*8 + j
//                      n = t*32 + (lane&31); k = s*16 + (lane>>5)*8 + j ; s in [0,32)
//   [262144, 264192)   d_fused f32[512]   (c/a shift)
//   [264192, 265216)   D_fc    f32[256]   (fc shift incl b0, scaled by 1/A)
//   [265216, 267264)   W1a     f32[512]   (W1 * A_fc)

__global__ __launch_bounds__(256) void setup_kernel(
    const float* __restrict__ W0,
    const float* __restrict__ imu_gamma, const float* __restrict__ imu_beta,
    const float* __restrict__ imu_mean,  const float* __restrict__ imu_var,
    const float* __restrict__ frame_gamma, const float* __restrict__ frame_beta,
    const float* __restrict__ frame_mean,  const float* __restrict__ frame_var,
    const float* __restrict__ b0,
    const float* __restrict__ fc_gamma, const float* __restrict__ fc_beta,
    const float* __restrict__ fc_mean,  const float* __restrict__ fc_var,
    const float* __restrict__ W1,
    void* __restrict__ ws)
{
    __bf16* w0p   = (__bf16*)ws;
    float* d_fused = (float*)((char*)ws + 262144);
    float* D_fc    = d_fused + 512;
    float* W1a     = D_fc + 256;

    const int b = blockIdx.x;
    if (b < 512) {
        const int flat = b * 256 + threadIdx.x;
        const int j    = flat & 7;
        const int lane = (flat >> 3) & 63;
        const int t    = (flat >> 9) & 7;
        const int s    = flat >> 12;                  // 0..31
        const int n    = t * 32 + (lane & 31);
        const int k    = s * 16 + ((lane >> 5) << 3) + j;
        const float a = (k < 256)
            ? frame_gamma[k] * rsqrtf(frame_var[k] + BN_EPS)
            : imu_gamma[k - 256] * rsqrtf(imu_var[k - 256] + BN_EPS);
        w0p[flat] = (__bf16)(W0[n * 512 + k] * a);
    } else {
        const int t = threadIdx.x;
        const float af = frame_gamma[t] * rsqrtf(frame_var[t] + BN_EPS);
        d_fused[t]       = frame_beta[t] / af - frame_mean[t];
        const float ai = imu_gamma[t] * rsqrtf(imu_var[t] + BN_EPS);
        d_fused[256 + t] = imu_beta[t] / ai - imu_mean[t];
        const float A = fc_gamma[t] * rsqrtf(fc_var[t] + BN_EPS);
        D_fc[t] = fc_beta[t] / A + b0[t] - fc_mean[t];
        W1a[t]       = W1[t] * A;
        W1a[256 + t] = W1[256 + t] * A;
    }
}

__global__ __launch_bounds__(TPB, 1) void fusion_main(
    const float* __restrict__ frame, const float* __restrict__ imu,
    const float* __restrict__ b1,    const void* __restrict__ ws_c,
    float* __restrict__ out)
{
    const __bf16* w0p = (const __bf16*)ws_c;
    const float*  d_g = (const float*)((const char*)ws_c + 262144);
    const float*  Dfc = d_g + 512;
    const float*  W1a = Dfc + 256;

    __shared__ __align__(16) __bf16 wpan[3][4096];      // 3 x 8 KB W0a k-step panels
    __shared__ __align__(16) float  fring[2][2][2048];  // [rg][slot] 64 rows x 32 f32 (8 KB)
    __shared__ float d_sh[512];
    __shared__ float cbuf[2][128][2];

    const int tid  = threadIdx.x;
    const int wave = tid >> 6;
    const int lane = tid & 63;
    const int cg   = wave & 1;     // col group (128 cols)
    const int rg   = wave >> 1;    // row group (64 rows)
    const int col  = lane & 31;
    const int hi   = lane >> 5;
    const size_t rowBlk = (size_t)blockIdx.x * BM;

    // F chunk (k=32): 64 rows x 128B contiguous/row. gll lane map: fr=lane>>3 (8 rows),
    // physical granule lane&7; stored holds logical (lane&7)^((lane>>3)&7) -> read swizzle r&7.
    const int fr = lane >> 3;
    const int fg = (lane & 7) ^ ((lane >> 3) & 7);

    auto issueF = [&](int c) {     // stage chunk c (phases 2c,2c+1); wave stages its cg's 32 rows
        const int cc = (c < 15) ? c : 15;
        const int slot = c & 1;                        // tail slots provably dead
        const float* srcp = (cc < 8) ? frame : imu;
        const int kb = (cc & 7) * 32;
        float* dstb = &fring[rg][slot][0];
        #pragma unroll
        for (int i = 0; i < 4; ++i)
            gll16(srcp + (rowBlk + rg * 64 + cg * 32 + i * 8 + fr) * 256 + kb + fg * 4,
                  dstb + (cg * 32 + i * 8) * 32);
    };
    auto issueW = [&](int e) {     // stage k-step panel e (8 KB), 2 KB per wave
        const int ee = (e < 31) ? e : 31;              // tail panels dead
        const char* src = (const char*)w0p + ee * 8192 + wave * 2048 + lane * 16;
        char* dst = (char*)&wpan[e % 3][0] + wave * 2048;
        gll16(src, dst);
        gll16(src + 1024, dst + 1024);
    };

    // ---- prologue ----
    d_sh[tid] = d_g[tid];
    d_sh[tid + 256] = d_g[tid + 256];
    asm volatile("s_waitcnt vmcnt(0)" ::: "memory");
    issueW(0);        // 2
    issueF(0);        // 4
    issueW(1);        // 2
    WAITVM(2);        // retire W0,F0; keep W1
    asm volatile("s_waitcnt lgkmcnt(0)" ::: "memory");
    __builtin_amdgcn_s_barrier();

    f32x16 acc[2][4];
    #pragma unroll
    for (int m = 0; m < 2; ++m)
        #pragma unroll
        for (int t = 0; t < 4; ++t)
            #pragma unroll
            for (int r = 0; r < 16; ++r) acc[m][t][r] = 0.f;

    auto stepc = [&](int s) {
        const float* sb = &fring[rg][(s >> 1) & 1][0];
        const __bf16* pan = &wpan[s % 3][0];
        const int kf = s * 16 + hi * 8;
        const f32x4 d0 = *(const f32x4*)(d_sh + kf);
        const f32x4 d1 = *(const f32x4*)(d_sh + kf + 4);
        const int g0 = (s & 1) * 4 + hi * 2;
        const int sw = col & 7;
        bf16x8 af[2];
        #pragma unroll
        for (int m = 0; m < 2; ++m) {
            const int rc = m * 32 + col;
            const f32x4 x0 = *(const f32x4*)(sb + rc * 32 + (((g0 + 0) ^ sw) << 2));
            const f32x4 x1 = *(const f32x4*)(sb + rc * 32 + (((g0 + 1) ^ sw) << 2));
            af[m][0] = (__bf16)fmaxf(x0[0] + d0[0], 0.f);
            af[m][1] = (__bf16)fmaxf(x0[1] + d0[1], 0.f);
            af[m][2] = (__bf16)fmaxf(x0[2] + d0[2], 0.f);
            af[m][3] = (__bf16)fmaxf(x0[3] + d0[3], 0.f);
            af[m][4] = (__bf16)fmaxf(x1[0] + d1[0], 0.f);
            af[m][5] = (__bf16)fmaxf(x1[1] + d1[1], 0.f);
            af[m][6] = (__bf16)fmaxf(x1[2] + d1[2], 0.f);
            af[m][7] = (__bf16)fmaxf(x1[3] + d1[3], 0.f);
        }
        #pragma unroll
        for (int tt = 0; tt < 4; ++tt) {
            const bf16x8 bfr = *(const bf16x8*)(pan + ((cg * 4 + tt) * 64 + lane) * 8);
            acc[0][tt] = __builtin_amdgcn_mfma_f32_32x32x16_bf16(af[0], bfr, acc[0][tt], 0, 0, 0);
            acc[1][tt] = __builtin_amdgcn_mfma_f32_32x32x16_bf16(af[1], bfr, acc[1][tt], 0, 0, 0);
        }
    };

    // steady: queue before wait always 8.
    //   even s: +W(s+2) +F(s/2+1) -> stepc(s) -> WAITVM(6) retires W(s+1) (and older)
    //   odd  s: +W(s+2)           -> stepc(s) -> WAITVM(2) retires W(s+1), F(cur+1)
    // every consumed gll: retired at previous phase's wait, then barrier, then read.
    #pragma unroll
    for (int s = 0; s < 32; ++s) {
        issueW(s + 2);
        if ((s & 1) == 0) issueF((s >> 1) + 1);
        stepc(s);
        if ((s & 1) == 0) { WAITVM(6); } else { WAITVM(2); }
        __builtin_amdgcn_s_barrier();
    }
    WAITVM(0);   // drain dangling tail glls

    // ---- epilogue: fc shift+ReLU + (W1*A) dot + cross-cg combine + ReLU + clamp ----
    // C/D (32x32): col = (cg*4+tt)*32 + col, row-in-tile = (r&3) + 8*(r>>2) + 4*hi
    float Dv[4], w0v[4], w1v[4];
    #pragma unroll
    for (int tt = 0; tt < 4; ++tt) {
        const int n = cg * 128 + tt * 32 + col;
        Dv[tt]  = Dfc[n];
        w0v[tt] = W1a[n];
        w1v[tt] = W1a[256 + n];
    }
    #pragma unroll
    for (int m = 0; m < 2; ++m) {
        float p0[16], p1[16];
        #pragma unroll
        for (int r = 0; r < 16; ++r) { p0[r] = 0.f; p1[r] = 0.f; }
        #pragma unroll
        for (int tt = 0; tt < 4; ++tt) {
            #pragma unroll
            for (int r = 0; r < 16; ++r) {
                const float h = fmaxf(acc[m][tt][r] + Dv[tt], 0.f);
                p0[r] = fmaf(h, w0v[tt], p0[r]);
                p1[r] = fmaf(h, w1v[tt], p1[r]);
            }
        }
        #pragma unroll
        for (int off = 1; off < 32; off <<= 1) {
            #pragma unroll
            for (int r = 0; r < 16; ++r) {
                p0[r] += __shfl_xor(p0[r], off, 64);
                p1[r] += __shfl_xor(p1[r], off, 64);
            }
        }
        if (col == 0) {
            #pragma unroll
            for (int r = 0; r < 16; ++r) {
                const int rb = (r & 3) + 8 * (r >> 2) + 4 * hi;
                const int rowb = rg * 64 + m * 32 + rb;
                cbuf[cg][rowb][0] = p0[r];
                cbuf[cg][rowb][1] = p1[r];
            }
        }
    }
    __syncthreads();
    if (tid < 128) {
        const float v0 = fminf(fmaxf(cbuf[0][tid][0] + cbuf[1][tid][0] + b1[0], 0.f), 512.f);
        const float v1 = fminf(fmaxf(cbuf[0][tid][1] + cbuf[1][tid][1] + b1[1], 0.f), 384.f);
        *(float2*)(out + (rowBlk + tid) * 2) = make_float2(v0, v1);
    }
}

extern "C" void kernel_launch(void* const* d_in, const int* in_sizes, int n_in,
                              void* d_out, int out_size, void* d_ws, size_t ws_size,
                              hipStream_t stream) {
    const float* frame_feat  = (const float*)d_in[0];
    const float* imu_feat    = (const float*)d_in[1];
    const float* imu_gamma   = (const float*)d_in[2];
    const float* imu_beta    = (const float*)d_in[3];
    const float* imu_mean    = (const float*)d_in[4];
    const float* imu_var     = (const float*)d_in[5];
    const float* frame_gamma = (const float*)d_in[6];
    const float* frame_beta  = (const float*)d_in[7];
    const float* frame_mean  = (const float*)d_in[8];
    const float* frame_var   = (const float*)d_in[9];
    const float* W0          = (const float*)d_in[10];
    const float* b0          = (const float*)d_in[11];
    const float* fc_gamma    = (const float*)d_in[12];
    const float* fc_beta     = (const float*)d_in[13];
    const float* fc_mean     = (const float*)d_in[14];
    const float* fc_var      = (const float*)d_in[15];
    const float* W1          = (const float*)d_in[16];
    const float* b1          = (const float*)d_in[17];

    setup_kernel<<<513, 256, 0, stream>>>(
        W0, imu_gamma, imu_beta, imu_mean, imu_var,
        frame_gamma, frame_beta, frame_mean, frame_var,
        b0, fc_gamma, fc_beta, fc_mean, fc_var, W1, d_ws);

    fusion_main<<<NBLOCKS, TPB, 0, stream>>>(
        frame_feat, imu_feat, b1, d_ws, (float*)d_out);
}

// Round 13
// 78.156 us; speedup vs baseline: 1.4540x; 1.4540x over previous
//
#include <hip/hip_runtime.h>
#include <hip/hip_bf16.h>

typedef __bf16 bf16x8 __attribute__((ext_vector_type(8)));
typedef float  f32x4  __attribute__((ext_vector_type(4)));
typedef float  f32x16 __attribute__((ext_vector_type(16)));

#define BN_EPS 1e-5f
#define NROWS 131072
#define TPB 256               // 4 waves; wave owns 32 rows x all 256 cols
#define BM 128                // rows per block
#define NBLOCKS (NROWS / BM)  // 1024

#define WAITVM(N) asm volatile("s_waitcnt vmcnt(" #N ")" ::: "memory")

__device__ __forceinline__ void gll16(const void* g, void* l) {
    __builtin_amdgcn_global_load_lds(
        (const __attribute__((address_space(1))) void*)g,
        (__attribute__((address_space(3))) void*)l, 16, 0, 0);
}

// ws layout (bytes):
//   [0, 262144)        W0a packed bf16 (BN scale a folded in) for 32x32x16 B-frags:
//                      flat = ((s*8 + t)*64 + lane)*8 + j
//                      n = t*32 + (lane&31); k = s*16 + (lane>>5)*8 + j ; s in [0,32)
//   [262144, 264192)   d_fused f32[512]   (c/a shift)
//   [264192, 265216)   D_fc    f32[256]   (fc shift incl b0, scaled by 1/A)
//   [265216, 267264)   W1a     f32[512]   (W1 * A_fc)

__global__ __launch_bounds__(256) void setup_kernel(
    const float* __restrict__ W0,
    const float* __restrict__ imu_gamma, const float* __restrict__ imu_beta,
    const float* __restrict__ imu_mean,  const float* __restrict__ imu_var,
    const float* __restrict__ frame_gamma, const float* __restrict__ frame_beta,
    const float* __restrict__ frame_mean,  const float* __restrict__ frame_var,
    const float* __restrict__ b0,
    const float* __restrict__ fc_gamma, const float* __restrict__ fc_beta,
    const float* __restrict__ fc_mean,  const float* __restrict__ fc_var,
    const float* __restrict__ W1,
    void* __restrict__ ws)
{
    __bf16* w0p   = (__bf16*)ws;
    float* d_fused = (float*)((char*)ws + 262144);
    float* D_fc    = d_fused + 512;
    float* W1a     = D_fc + 256;

    const int b = blockIdx.x;
    if (b < 512) {
        const int flat = b * 256 + threadIdx.x;
        const int j    = flat & 7;
        const int lane = (flat >> 3) & 63;
        const int t    = (flat >> 9) & 7;
        const int s    = flat >> 12;                  // 0..31
        const int n    = t * 32 + (lane & 31);
        const int k    = s * 16 + ((lane >> 5) << 3) + j;
        const float a = (k < 256)
            ? frame_gamma[k] * rsqrtf(frame_var[k] + BN_EPS)
            : imu_gamma[k - 256] * rsqrtf(imu_var[k - 256] + BN_EPS);
        w0p[flat] = (__bf16)(W0[n * 512 + k] * a);
    } else {
        const int t = threadIdx.x;
        const float af = frame_gamma[t] * rsqrtf(frame_var[t] + BN_EPS);
        d_fused[t]       = frame_beta[t] / af - frame_mean[t];
        const float ai = imu_gamma[t] * rsqrtf(imu_var[t] + BN_EPS);
        d_fused[256 + t] = imu_beta[t] / ai - imu_mean[t];
        const float A = fc_gamma[t] * rsqrtf(fc_var[t] + BN_EPS);
        D_fc[t] = fc_beta[t] / A + b0[t] - fc_mean[t];
        W1a[t]       = W1[t] * A;
        W1a[256 + t] = W1[256 + t] * A;
    }
}

__global__ __launch_bounds__(TPB, 1) void fusion_main(
    const float* __restrict__ frame, const float* __restrict__ imu,
    const float* __restrict__ b1,    const void* __restrict__ ws_c,
    float* __restrict__ out)
{
    const __bf16* w0p = (const __bf16*)ws_c;
    const float*  d_g = (const float*)((const char*)ws_c + 262144);
    const float*  Dfc = d_g + 512;
    const float*  W1a = Dfc + 256;

    // 26.6 KB LDS -> ~6 blocks/CU
    __shared__ __align__(16) __bf16 wpan[3][4096];   // 3 x 8 KB W0a k-step panels
    __shared__ float d_sh[512];

    const int tid  = threadIdx.x;
    const int wave = tid >> 6;
    const int lane = tid & 63;
    const int row  = lane & 31;   // A-frag row / C col index
    const int hi   = lane >> 5;
    const size_t rowW = (size_t)blockIdx.x * BM + wave * 32;

    auto issueW = [&](int e) {     // stage k-step panel e (8 KB), 2 KB per wave
        const int ee = (e < 31) ? e : 31;              // tail panels dead
        const char* src = (const char*)w0p + ee * 8192 + wave * 2048 + lane * 16;
        char* dst = (char*)&wpan[e % 3][0] + wave * 2048;
        gll16(src, dst);
        gll16(src + 1024, dst + 1024);
    };
    auto loadF = [&](int c, float4& f0, float4& f1) {   // features direct to VGPR
        const int cc = (c < 32) ? c : 31;
        const float* srcp = (cc < 16) ? frame : imu;
        const float* xp = srcp + (rowW + row) * 256 + (cc & 15) * 16 + hi * 8;
        f0 = *(const float4*)xp;
        f1 = *(const float4*)(xp + 4);
    };

    // ---- prologue ----
    d_sh[tid] = d_g[tid];
    d_sh[tid + 256] = d_g[tid + 256];
    asm volatile("s_waitcnt vmcnt(0)" ::: "memory");   // clean vm queue for counted waits
    issueW(0);
    issueW(1);
    float4 fA0, fA1, fB0, fB1;
    loadF(0, fA0, fA1);
    WAITVM(4);                    // retire W(0); keep [W(1), F(0)]
    asm volatile("s_waitcnt lgkmcnt(0)" ::: "memory");
    __builtin_amdgcn_s_barrier();

    f32x16 acc[8];
    #pragma unroll
    for (int t = 0; t < 8; ++t)
        #pragma unroll
        for (int r = 0; r < 16; ++r) acc[t][r] = 0.f;

    auto stepc = [&](int s, const float4& x0, const float4& x1) {
        const int kf = s * 16 + hi * 8;
        const f32x4 d0 = *(const f32x4*)(d_sh + kf);
        const f32x4 d1 = *(const f32x4*)(d_sh + kf + 4);
        bf16x8 af;
        af[0] = (__bf16)fmaxf(x0.x + d0[0], 0.f);
        af[1] = (__bf16)fmaxf(x0.y + d0[1], 0.f);
        af[2] = (__bf16)fmaxf(x0.z + d0[2], 0.f);
        af[3] = (__bf16)fmaxf(x0.w + d0[3], 0.f);
        af[4] = (__bf16)fmaxf(x1.x + d1[0], 0.f);
        af[5] = (__bf16)fmaxf(x1.y + d1[1], 0.f);
        af[6] = (__bf16)fmaxf(x1.z + d1[2], 0.f);
        af[7] = (__bf16)fmaxf(x1.w + d1[3], 0.f);
        const __bf16* pan = &wpan[s % 3][0];
        #pragma unroll
        for (int t = 0; t < 8; ++t) {
            const bf16x8 bfr = *(const bf16x8*)(pan + (t * 64 + lane) * 8);
            acc[t] = __builtin_amdgcn_mfma_f32_32x32x16_bf16(af, bfr, acc[t], 0, 0, 0);
        }
    };

    // steady phase s: entering queue [W(s+1), F(s)] (4 ops)
    //   +W(s+2) +F(s+1) -> compute(s) (compiler waits F(s), retiring W(s+1) with it)
    //   -> WAITVM(4) guarantees W(s+1) retired -> barrier
    #pragma unroll
    for (int s = 0; s < 32; ++s) {
        issueW(s + 2);
        if ((s & 1) == 0) { loadF(s + 1, fB0, fB1); stepc(s, fA0, fA1); }
        else              { loadF(s + 1, fA0, fA1); stepc(s, fB0, fB1); }
        WAITVM(4);
        __builtin_amdgcn_s_barrier();
    }
    WAITVM(0);   // drain tail glls

    // ---- epilogue: fc shift+ReLU + (W1*A) dot + ReLU + clamp (wave-local) ----
    // C/D (32x32): col = t*32 + row, row-in-tile = (r&3) + 8*(r>>2) + 4*hi
    const float b1_0 = b1[0], b1_1 = b1[1];
    float p0[16], p1[16];
    #pragma unroll
    for (int r = 0; r < 16; ++r) { p0[r] = 0.f; p1[r] = 0.f; }

    #pragma unroll
    for (int t = 0; t < 8; ++t) {
        const int n = t * 32 + row;
        const float D = Dfc[n];
        const float w0n = W1a[n], w1n = W1a[256 + n];
        #pragma unroll
        for (int r = 0; r < 16; ++r) {
            const float h = fmaxf(acc[t][r] + D, 0.f);
            p0[r] = fmaf(h, w0n, p0[r]);
            p1[r] = fmaf(h, w1n, p1[r]);
        }
    }
    #pragma unroll
    for (int off = 1; off < 32; off <<= 1) {
        #pragma unroll
        for (int r = 0; r < 16; ++r) {
            p0[r] += __shfl_xor(p0[r], off, 64);
            p1[r] += __shfl_xor(p1[r], off, 64);
        }
    }
    if (row == 0) {   // lanes 0 and 32 each write 16 rows
        #pragma unroll
        for (int r = 0; r < 16; ++r) {
            const int rbase = (r & 3) + 8 * (r >> 2) + 4 * hi;
            const float v0 = fminf(fmaxf(p0[r] + b1_0, 0.f), 512.f);
            const float v1 = fminf(fmaxf(p1[r] + b1_1, 0.f), 384.f);
            *(float2*)(out + (rowW + rbase) * 2) = make_float2(v0, v1);
        }
    }
}

extern "C" void kernel_launch(void* const* d_in, const int* in_sizes, int n_in,
                              void* d_out, int out_size, void* d_ws, size_t ws_size,
                              hipStream_t stream) {
    const float* frame_feat  = (const float*)d_in[0];
    const float* imu_feat    = (const float*)d_in[1];
    const float* imu_gamma   = (const float*)d_in[2];
    const float* imu_beta    = (const float*)d_in[3];
    const float* imu_mean    = (const float*)d_in[4];
    const float* imu_var     = (const float*)d_in[5];
    const float* frame_gamma = (const float*)d_in[6];
    const float* frame_beta  = (const float*)d_in[7];
    const float* frame_mean  = (const float*)d_in[8];
    const float* frame_var   = (const float*)d_in[9];
    const float* W0          = (const float*)d_in[10];
    const float* b0          = (const float*)d_in[11];
    const float* fc_gamma    = (const float*)d_in[12];
    const float* fc_beta     = (const float*)d_in[13];
    const float* fc_mean     = (const float*)d_in[14];
    const float* fc_var      = (const float*)d_in[15];
    const float* W1          = (const float*)d_in[16];
    const float* b1          = (const float*)d_in[17];

    setup_kernel<<<513, 256, 0, stream>>>(
        W0, imu_gamma, imu_beta, imu_mean, imu_var,
        frame_gamma, frame_beta, frame_mean, frame_var,
        b0, fc_gamma, fc_beta, fc_mean, fc_var, W1, d_ws);

    fusion_main<<<NBLOCKS, TPB, 0, stream>>>(
        frame_feat, imu_feat, b1, d_ws, (float*)d_out);
}